// Round 1
// baseline (2046.800 us; speedup 1.0000x reference)
//
#include <hip/hip_runtime.h>
#include <float.h>

#define EPSF 1e-6f

constexpr int Bc = 4, Tc = 4096, Dc = 512, Kc = 4096, DOc = 1024;
constexpr int Mc = Bc * Tc;            // 16384 rows
constexpr int NCH = 4;                 // center-chunks for dist kernel (occupancy)
constexpr int KCH = Kc / NCH;          // 1024 centers per chunk
constexpr float TAU = 0.05f;           // fp64-refine trigger margin (fp32 err ~2e-3)

__device__ __forceinline__ void top2_merge(float v, int n, float& bv1, int& bi1,
                                           float& bv2, int& bi2) {
  // strict ordering with first-occurrence (lowest index) tie-break, matches np.argmin
  if (v < bv1 || (v == bv1 && n < bi1)) { bv2 = bv1; bi2 = bi1; bv1 = v; bi1 = n; }
  else if (v < bv2 || (v == bv2 && n < bi2)) { bv2 = v; bi2 = n; }
}

// ---------------- kernel 1: c2[k] = sum_d centers[k][d]^2 ----------------
__global__ __launch_bounds__(256) void c2_kernel(const float* __restrict__ centers,
                                                 float* __restrict__ c2) {
  const int lane = threadIdx.x & 63;
  const int wave = threadIdx.x >> 6;
  const int k = blockIdx.x * 4 + wave;
  const float* row = centers + (size_t)k * Dc;
  float4 v0 = *(const float4*)(row + lane * 8);
  float4 v1 = *(const float4*)(row + lane * 8 + 4);
  float s = v0.x * v0.x + v0.y * v0.y + v0.z * v0.z + v0.w * v0.w
          + v1.x * v1.x + v1.y * v1.y + v1.z * v1.z + v1.w * v1.w;
#pragma unroll
  for (int off = 32; off > 0; off >>= 1) s += __shfl_down(s, off, 64);
  if (lane == 0) c2[k] = s;
}

// ------- kernel 2: per (64-row block, 1024-center chunk) top-2 of d2' -------
// d2' = c2[n] - 2*dot(x+eps, c[n])  (x2 row-constant dropped; argmin invariant)
__global__ __launch_bounds__(256) void dist_top2_kernel(
    const float* __restrict__ x, const float* __restrict__ centers,
    const float* __restrict__ c2, float4* __restrict__ part) {
  constexpr int MT = 64, NT = 128, DK = 16, PAD = 20;  // pad 20: 16B-aligned rows, 2-way LDS aliasing (free)
  __shared__ float xs[MT][PAD];
  __shared__ float cs[NT][PAD];
  __shared__ float redv1[MT][17];
  __shared__ int   redi1[MT][17];
  __shared__ float redv2[MT][17];
  __shared__ int   redi2[MT][17];

  const int row0 = blockIdx.x * MT;
  const int nbase = blockIdx.y * KCH;
  const int tid = threadIdx.x;
  const int tx = tid & 15, ty = tid >> 4;

  float bv1 = FLT_MAX, bv2 = FLT_MAX;
  int bi1 = 0, bi2 = 0;

  for (int nt = 0; nt < KCH; nt += NT) {
    const int n0 = nbase + nt;
    float acc[4][8];
#pragma unroll
    for (int i = 0; i < 4; ++i)
#pragma unroll
      for (int j = 0; j < 8; ++j) acc[i][j] = 0.f;

    for (int d0 = 0; d0 < Dc; d0 += DK) {
      {
        const int r = tid >> 2, c4 = (tid & 3) << 2;
        float4 v = *(const float4*)(x + (size_t)(row0 + r) * Dc + d0 + c4);
        v.x += EPSF; v.y += EPSF; v.z += EPSF; v.w += EPSF;
        *(float4*)&xs[r][c4] = v;
      }
#pragma unroll
      for (int rr = 0; rr < 2; ++rr) {
        const int li = tid + rr * 256;
        const int r = li >> 2, c4 = (li & 3) << 2;
        *(float4*)&cs[r][c4] =
            *(const float4*)(centers + (size_t)(n0 + r) * Dc + d0 + c4);
      }
      __syncthreads();
#pragma unroll
      for (int dk = 0; dk < DK; ++dk) {
        float xv[4], cv[8];
#pragma unroll
        for (int i = 0; i < 4; ++i) xv[i] = xs[ty * 4 + i][dk];
#pragma unroll
        for (int j = 0; j < 8; ++j) cv[j] = cs[tx + 16 * j][dk];
#pragma unroll
        for (int i = 0; i < 4; ++i)
#pragma unroll
          for (int j = 0; j < 8; ++j) acc[i][j] = fmaf(xv[i], cv[j], acc[i][j]);
      }
      __syncthreads();
    }

    // per-thread top2 over its 8 centers, per row
#pragma unroll
    for (int i = 0; i < 4; ++i) {
      float v1 = FLT_MAX, v2 = FLT_MAX;
      int i1 = 0, i2 = 0;
#pragma unroll
      for (int j = 0; j < 8; ++j) {
        const int n = n0 + tx + 16 * j;
        const float d = c2[n] - 2.0f * acc[i][j];
        top2_merge(d, n, v1, i1, v2, i2);
      }
      const int r = ty * 4 + i;
      redv1[r][tx] = v1; redi1[r][tx] = i1;
      redv2[r][tx] = v2; redi2[r][tx] = i2;
    }
    __syncthreads();
    if (tid < MT) {
      for (int t = 0; t < 16; ++t) {
        top2_merge(redv1[tid][t], redi1[tid][t], bv1, bi1, bv2, bi2);
        top2_merge(redv2[tid][t], redi2[tid][t], bv1, bi1, bv2, bi2);
      }
    }
    __syncthreads();
  }

  if (tid < MT) {
    float4 p;
    p.x = bv1; p.y = __int_as_float(bi1);
    p.z = bv2; p.w = __int_as_float(bi2);
    part[(size_t)(row0 + tid) * NCH + blockIdx.y] = p;
  }
}

// ---------------- kernel 3: merge chunks, fp64-refine near-ties ----------------
__device__ double refine_d2(const float* __restrict__ xr,
                            const float* __restrict__ cr) {
  double dot = 0.0, cc = 0.0;
  for (int d = 0; d < Dc; ++d) {
    const float xq = xr[d] + EPSF;  // fp32 rounding of x+eps, matching reference
    const double cd = (double)cr[d];
    dot += (double)xq * cd;
    cc += cd * cd;
  }
  return cc - 2.0 * dot;
}

__global__ __launch_bounds__(256) void merge_refine_kernel(
    const float* __restrict__ x, const float* __restrict__ centers,
    const float4* __restrict__ part, int* __restrict__ sel) {
  const int row = blockIdx.x * 256 + threadIdx.x;
  float bv1 = FLT_MAX, bv2 = FLT_MAX;
  int bi1 = 0, bi2 = 0;
  for (int c = 0; c < NCH; ++c) {
    const float4 p = part[(size_t)row * NCH + c];
    top2_merge(p.x, __float_as_int(p.y), bv1, bi1, bv2, bi2);
    top2_merge(p.z, __float_as_int(p.w), bv1, bi1, bv2, bi2);
  }
  int choice = bi1;
  if (bv2 - bv1 < TAU) {
    const double da = refine_d2(x + (size_t)row * Dc, centers + (size_t)bi1 * Dc);
    const double db = refine_d2(x + (size_t)row * Dc, centers + (size_t)bi2 * Dc);
    if (db < da || (db == da && bi2 < bi1)) choice = bi2;
  }
  sel[row] = choice;
}

// ---------------- kernel 4: out = centers[sel] @ W + b ----------------
__global__ __launch_bounds__(256) void proj_kernel(
    const float* __restrict__ centers, const int* __restrict__ sel,
    const float* __restrict__ W, const float* __restrict__ bias,
    float* __restrict__ out) {
  constexpr int MT = 64, NT = 128, DK = 16, PAD = 20;
  __shared__ float qs[MT][PAD];
  __shared__ float wsm[DK][NT];
  __shared__ int ssel[MT];
  const int row0 = blockIdx.x * MT;
  const int n0 = blockIdx.y * NT;
  const int tid = threadIdx.x;
  const int tx = tid & 15, ty = tid >> 4;
  if (tid < MT) ssel[tid] = sel[row0 + tid];
  __syncthreads();

  float acc[4][8];
#pragma unroll
  for (int i = 0; i < 4; ++i)
#pragma unroll
    for (int j = 0; j < 8; ++j) acc[i][j] = 0.f;

  for (int d0 = 0; d0 < Dc; d0 += DK) {
    {
      const int r = tid >> 2, c4 = (tid & 3) << 2;
      *(float4*)&qs[r][c4] =
          *(const float4*)(centers + (size_t)ssel[r] * Dc + d0 + c4);
    }
#pragma unroll
    for (int rr = 0; rr < 2; ++rr) {
      const int li = tid + rr * 256;
      const int dk = li >> 5, c4 = (li & 31) << 2;
      *(float4*)&wsm[dk][c4] =
          *(const float4*)(W + (size_t)(d0 + dk) * DOc + n0 + c4);
    }
    __syncthreads();
#pragma unroll
    for (int dk = 0; dk < DK; ++dk) {
      float xv[4], wv[8];
#pragma unroll
      for (int i = 0; i < 4; ++i) xv[i] = qs[ty * 4 + i][dk];
#pragma unroll
      for (int j = 0; j < 8; ++j) wv[j] = wsm[dk][tx + 16 * j];
#pragma unroll
      for (int i = 0; i < 4; ++i)
#pragma unroll
        for (int j = 0; j < 8; ++j) acc[i][j] = fmaf(xv[i], wv[j], acc[i][j]);
    }
    __syncthreads();
  }

#pragma unroll
  for (int j = 0; j < 8; ++j) {
    const int col = n0 + tx + 16 * j;
    const float bb = bias[col];
#pragma unroll
    for (int i = 0; i < 4; ++i)
      out[(size_t)(row0 + ty * 4 + i) * DOc + col] = acc[i][j] + bb;
  }
}

extern "C" void kernel_launch(void* const* d_in, const int* in_sizes, int n_in,
                              void* d_out, int out_size, void* d_ws, size_t ws_size,
                              hipStream_t stream) {
  const float* x = (const float*)d_in[0];        // [4,4096,512]
  const float* centers = (const float*)d_in[1];  // [4096,512]
  const float* W = (const float*)d_in[2];        // [512,1024]
  const float* b = (const float*)d_in[3];        // [1024]
  float* out = (float*)d_out;                    // [4,4096,1024] fp32

  // workspace layout (~1.1 MB): c2 | part(top2 per row per chunk) | sel
  char* ws = (char*)d_ws;
  float* c2 = (float*)ws;                                   // 4096 f = 16 KB
  float4* part = (float4*)(ws + 16384);                     // 16384*4*16B = 1 MB
  int* sel = (int*)(ws + 16384 + (size_t)Mc * NCH * 16);    // 64 KB

  c2_kernel<<<Kc / 4, 256, 0, stream>>>(centers, c2);
  dist_top2_kernel<<<dim3(Mc / 64, NCH), 256, 0, stream>>>(x, centers, c2, part);
  merge_refine_kernel<<<Mc / 256, 256, 0, stream>>>(x, centers, part, sel);
  proj_kernel<<<dim3(Mc / 64, DOc / 128), 256, 0, stream>>>(centers, sel, W, b, out);
}

// Round 2
// 749.098 us; speedup vs baseline: 2.7324x; 2.7324x over previous
//
#include <hip/hip_runtime.h>
#include <float.h>
#include <stdint.h>

#define EPSF 1e-6f

constexpr int Dc = 512, Kc = 4096, DOc = 1024;
constexpr int Mc = 16384;                 // 4*4096 rows
constexpr int NB = Kc / 128;              // 32 N-chunks in dist kernel
constexpr float TAU = 0.02f;              // fp64-refine trigger (split-f16 err ~1e-4)

typedef _Float16 f16x8 __attribute__((ext_vector_type(8)));
typedef float f32x4 __attribute__((ext_vector_type(4)));
typedef __attribute__((address_space(1))) unsigned int gu32;
typedef __attribute__((address_space(3))) unsigned int lu32;
typedef unsigned long long u64;

struct Key2 { u64 k1, k2; };

__device__ __forceinline__ void kmerge(u64 k, u64& k1, u64& k2) {
  if (k < k1) { k2 = k1; k1 = k; } else if (k < k2) { k2 = k; }
}
__device__ __forceinline__ u64 fkey(float v, int n) {
  uint32_t u = __float_as_uint(v);
  uint32_t s = u ^ (0x80000000u | (uint32_t)((int32_t)u >> 31));  // sortable
  return ((u64)s << 32) | (uint32_t)n;
}
__device__ __forceinline__ float keyval(u64 k) {
  uint32_t s = (uint32_t)(k >> 32);
  uint32_t u = (s & 0x80000000u) ? (s ^ 0x80000000u) : ~s;
  return __uint_as_float(u);
}
__device__ __forceinline__ int keyidx(u64 k) { return (int)(k & 0xFFFFFFFFu); }

// ---------- convert kernels: split-f16 hi/lo + c2 + W^T ----------
__global__ __launch_bounds__(256) void cvt_x_kernel(const float* __restrict__ x,
                                                    _Float16* __restrict__ xh,
                                                    _Float16* __restrict__ xl) {
  const size_t g = (size_t)blockIdx.x * 256 + threadIdx.x;
  const size_t base = g * 8;
  float4 v0 = *(const float4*)(x + base);
  float4 v1 = *(const float4*)(x + base + 4);
  float v[8] = {v0.x, v0.y, v0.z, v0.w, v1.x, v1.y, v1.z, v1.w};
  f16x8 h, l;
#pragma unroll
  for (int i = 0; i < 8; ++i) {
    const float q = v[i] + EPSF;
    const _Float16 hi = (_Float16)q;
    h[i] = hi;
    l[i] = (_Float16)(q - (float)hi);
  }
  *(f16x8*)(xh + base) = h;
  *(f16x8*)(xl + base) = l;
}

__global__ __launch_bounds__(256) void cvt_c_kernel(const float* __restrict__ centers,
                                                    _Float16* __restrict__ ch,
                                                    _Float16* __restrict__ cl,
                                                    float* __restrict__ c2) {
  const int lane = threadIdx.x & 63, w = threadIdx.x >> 6;
  const int row = blockIdx.x * 4 + w;
  const size_t base = (size_t)row * Dc + lane * 8;
  float4 v0 = *(const float4*)(centers + base);
  float4 v1 = *(const float4*)(centers + base + 4);
  float v[8] = {v0.x, v0.y, v0.z, v0.w, v1.x, v1.y, v1.z, v1.w};
  f16x8 h, l;
  float s = 0.f;
#pragma unroll
  for (int i = 0; i < 8; ++i) {
    s += v[i] * v[i];
    const _Float16 hi = (_Float16)v[i];
    h[i] = hi;
    l[i] = (_Float16)(v[i] - (float)hi);
  }
  *(f16x8*)(ch + base) = h;
  *(f16x8*)(cl + base) = l;
#pragma unroll
  for (int off = 32; off > 0; off >>= 1) s += __shfl_down(s, off, 64);
  if (lane == 0) c2[row] = s;
}

__global__ __launch_bounds__(256) void cvt_w_kernel(const float* __restrict__ W,
                                                    _Float16* __restrict__ whT) {
  const int g = blockIdx.x * 256 + threadIdx.x;  // 65536 threads
  const int n = g & (DOc - 1), d8 = g >> 10;
  f16x8 h;
#pragma unroll
  for (int r = 0; r < 8; ++r) h[r] = (_Float16)W[(size_t)(d8 * 8 + r) * DOc + n];
  *(f16x8*)(whT + (size_t)n * Dc + d8 * 8) = h;
}

// ---------- distance GEMM: split-f16 3-pass MFMA + per-chunk top-2 ----------
__global__ __launch_bounds__(256, 2) void dist_mfma_kernel(
    const _Float16* __restrict__ xh, const _Float16* __restrict__ xl,
    const _Float16* __restrict__ ch, const _Float16* __restrict__ cl,
    const float* __restrict__ c2, Key2* __restrict__ part) {
  constexpr int BM = 128, BN = 128, BK = 32;
  __shared__ __align__(16) _Float16 sAh[BM * BK], sAl[BM * BK];
  __shared__ __align__(16) _Float16 sBh[BN * BK], sBl[BN * BK];

  const int tid = threadIdx.x;
  const int lane = tid & 63, w = tid >> 6;
  const int row0 = blockIdx.x * BM;
  const int n0 = blockIdx.y * BN;
  const int srow = w * 16 + (lane >> 2);   // staging row (issue 0)
  const int scol = (lane & 3) * 8;         // staging col (f16 elems)
  const int fr = lane & 15, kq = lane >> 4;
  const int m0 = w * 32;                   // wave's 32-row strip

  f32x4 acc[2][8];
#pragma unroll
  for (int i = 0; i < 2; ++i)
#pragma unroll
    for (int j = 0; j < 8; ++j) acc[i][j] = (f32x4){0.f, 0.f, 0.f, 0.f};

  for (int d0 = 0; d0 < Dc; d0 += BK) {
#pragma unroll
    for (int r = 0; r < 2; ++r) {
      const int rr = r * 64 + srow;
      const size_t gA = (size_t)(row0 + rr) * Dc + d0 + scol;
      const size_t gB = (size_t)(n0 + rr) * Dc + d0 + scol;
      const int lo = rr * BK + scol;
      __builtin_amdgcn_global_load_lds((const gu32*)(xh + gA), (lu32*)(sAh + lo), 16, 0, 0);
      __builtin_amdgcn_global_load_lds((const gu32*)(xl + gA), (lu32*)(sAl + lo), 16, 0, 0);
      __builtin_amdgcn_global_load_lds((const gu32*)(ch + gB), (lu32*)(sBh + lo), 16, 0, 0);
      __builtin_amdgcn_global_load_lds((const gu32*)(cl + gB), (lu32*)(sBl + lo), 16, 0, 0);
    }
    __syncthreads();

    f16x8 ah[2], al[2], bh[8], bl[8];
#pragma unroll
    for (int i = 0; i < 2; ++i) {
      ah[i] = *(const f16x8*)&sAh[(m0 + 16 * i + fr) * BK + kq * 8];
      al[i] = *(const f16x8*)&sAl[(m0 + 16 * i + fr) * BK + kq * 8];
    }
#pragma unroll
    for (int j = 0; j < 8; ++j) {
      bh[j] = *(const f16x8*)&sBh[(16 * j + fr) * BK + kq * 8];
      bl[j] = *(const f16x8*)&sBl[(16 * j + fr) * BK + kq * 8];
    }
#pragma unroll
    for (int i = 0; i < 2; ++i)
#pragma unroll
      for (int j = 0; j < 8; ++j) {
        acc[i][j] = __builtin_amdgcn_mfma_f32_16x16x32_f16(ah[i], bh[j], acc[i][j], 0, 0, 0);
        acc[i][j] = __builtin_amdgcn_mfma_f32_16x16x32_f16(ah[i], bl[j], acc[i][j], 0, 0, 0);
        acc[i][j] = __builtin_amdgcn_mfma_f32_16x16x32_f16(al[i], bh[j], acc[i][j], 0, 0, 0);
      }
    __syncthreads();
  }

  // epilogue: d2' = c2[n] - 2*dot; per-row top-2 over this 128-col chunk
  float c2v[8];
#pragma unroll
  for (int j = 0; j < 8; ++j) c2v[j] = c2[n0 + 16 * j + fr];

#pragma unroll
  for (int i = 0; i < 2; ++i)
#pragma unroll
    for (int reg = 0; reg < 4; ++reg) {
      u64 k1 = ~0ULL, k2 = ~0ULL;
#pragma unroll
      for (int j = 0; j < 8; ++j) {
        const float d = c2v[j] - 2.0f * acc[i][j][reg];
        kmerge(fkey(d, n0 + 16 * j + fr), k1, k2);
      }
#pragma unroll
      for (int m = 1; m < 16; m <<= 1) {
        u64 o1 = (u64)__shfl_xor((long long)k1, m, 64);
        u64 o2 = (u64)__shfl_xor((long long)k2, m, 64);
        kmerge(o1, k1, k2);
        kmerge(o2, k1, k2);
      }
      if (fr == 0) {
        const int row = row0 + m0 + 16 * i + 4 * kq + reg;
        part[(size_t)row * NB + blockIdx.y] = {k1, k2};
      }
    }
}

// ---------- merge chunks + fp64 refine near-ties ----------
__device__ double refine_d2(const float* __restrict__ xr,
                            const float* __restrict__ cr) {
  double dot = 0.0, cc = 0.0;
  for (int d = 0; d < Dc; ++d) {
    const float xq = xr[d] + EPSF;
    const double cd = (double)cr[d];
    dot += (double)xq * cd;
    cc += cd * cd;
  }
  return cc - 2.0 * dot;
}

__global__ __launch_bounds__(256) void merge_refine_kernel(
    const float* __restrict__ x, const float* __restrict__ centers,
    const Key2* __restrict__ part, int* __restrict__ sel) {
  const int row = blockIdx.x * 256 + threadIdx.x;
  u64 k1 = ~0ULL, k2 = ~0ULL;
  for (int c = 0; c < NB; ++c) {
    const Key2 p = part[(size_t)row * NB + c];
    kmerge(p.k1, k1, k2);
    kmerge(p.k2, k1, k2);
  }
  int i1 = keyidx(k1), i2 = keyidx(k2);
  int choice = i1;
  if (keyval(k2) - keyval(k1) < TAU) {
    const double da = refine_d2(x + (size_t)row * Dc, centers + (size_t)i1 * Dc);
    const double db = refine_d2(x + (size_t)row * Dc, centers + (size_t)i2 * Dc);
    if (db < da || (db == da && i2 < i1)) choice = i2;
  }
  sel[row] = choice;
}

// ---------- projection: out = centers[sel] @ W + b  (f16 MFMA) ----------
__global__ __launch_bounds__(256, 2) void proj_mfma_kernel(
    const _Float16* __restrict__ ch, const int* __restrict__ sel,
    const _Float16* __restrict__ whT, const float* __restrict__ bias,
    float* __restrict__ out) {
  constexpr int BM = 128, BN = 128, BK = 32;
  __shared__ __align__(16) _Float16 sA[BM * BK], sB[BN * BK];
  __shared__ int ssel[BM];

  const int tid = threadIdx.x;
  const int lane = tid & 63, w = tid >> 6;
  const int row0 = blockIdx.x * BM;
  const int n0 = blockIdx.y * BN;
  const int srow = w * 16 + (lane >> 2);
  const int scol = (lane & 3) * 8;
  const int fr = lane & 15, kq = lane >> 4;
  const int m0 = w * 32;

  if (tid < BM) ssel[tid] = sel[row0 + tid];
  __syncthreads();

  f32x4 acc[2][8];
#pragma unroll
  for (int i = 0; i < 2; ++i)
#pragma unroll
    for (int j = 0; j < 8; ++j) acc[i][j] = (f32x4){0.f, 0.f, 0.f, 0.f};

  for (int d0 = 0; d0 < Dc; d0 += BK) {
#pragma unroll
    for (int r = 0; r < 2; ++r) {
      const int rr = r * 64 + srow;
      const size_t gA = (size_t)ssel[rr] * Dc + d0 + scol;        // gathered row
      const size_t gB = (size_t)(n0 + rr) * Dc + d0 + scol;      // W^T row
      const int lo = rr * BK + scol;
      __builtin_amdgcn_global_load_lds((const gu32*)(ch + gA), (lu32*)(sA + lo), 16, 0, 0);
      __builtin_amdgcn_global_load_lds((const gu32*)(whT + gB), (lu32*)(sB + lo), 16, 0, 0);
    }
    __syncthreads();

    f16x8 a[2], b[8];
#pragma unroll
    for (int i = 0; i < 2; ++i)
      a[i] = *(const f16x8*)&sA[(m0 + 16 * i + fr) * BK + kq * 8];
#pragma unroll
    for (int j = 0; j < 8; ++j)
      b[j] = *(const f16x8*)&sB[(16 * j + fr) * BK + kq * 8];
#pragma unroll
    for (int i = 0; i < 2; ++i)
#pragma unroll
      for (int j = 0; j < 8; ++j)
        acc[i][j] = __builtin_amdgcn_mfma_f32_16x16x32_f16(a[i], b[j], acc[i][j], 0, 0, 0);
    __syncthreads();
  }

#pragma unroll
  for (int j = 0; j < 8; ++j) {
    const int col = n0 + 16 * j + fr;
    const float bb = bias[col];
#pragma unroll
    for (int i = 0; i < 2; ++i)
#pragma unroll
      for (int reg = 0; reg < 4; ++reg)
        out[(size_t)(row0 + m0 + 16 * i + 4 * kq + reg) * DOc + col] =
            acc[i][j][reg] + bb;
  }
}

extern "C" void kernel_launch(void* const* d_in, const int* in_sizes, int n_in,
                              void* d_out, int out_size, void* d_ws, size_t ws_size,
                              hipStream_t stream) {
  const float* x = (const float*)d_in[0];        // [4,4096,512]
  const float* centers = (const float*)d_in[1];  // [4096,512]
  const float* W = (const float*)d_in[2];        // [512,1024]
  const float* b = (const float*)d_in[3];        // [1024]
  float* out = (float*)d_out;                    // [4,4096,1024] fp32

  // workspace layout (~49.1 MB)
  char* ws = (char*)d_ws;
  _Float16* xh = (_Float16*)(ws);                        // 16.78 MB
  _Float16* xl = (_Float16*)(ws + 16777216);             // 16.78 MB
  _Float16* ch = (_Float16*)(ws + 33554432);             // 4.19 MB
  _Float16* cl = (_Float16*)(ws + 37748736);             // 4.19 MB
  _Float16* whT = (_Float16*)(ws + 41943040);            // 1.05 MB  [DO][D]
  float* c2 = (float*)(ws + 42991616);                   // 16 KB
  Key2* part = (Key2*)(ws + 43008000);                   // 8.39 MB  [M][32]
  int* sel = (int*)(ws + 51396608);                      // 64 KB

  cvt_x_kernel<<<Mc * Dc / (256 * 8), 256, 0, stream>>>(x, xh, xl);
  cvt_c_kernel<<<Kc / 4, 256, 0, stream>>>(centers, ch, cl, c2);
  cvt_w_kernel<<<Dc * DOc / (256 * 8), 256, 0, stream>>>(W, whT);
  dist_mfma_kernel<<<dim3(Mc / 128, Kc / 128), 256, 0, stream>>>(xh, xl, ch, cl, c2, part);
  merge_refine_kernel<<<Mc / 256, 256, 0, stream>>>(x, centers, part, sel);
  proj_mfma_kernel<<<dim3(Mc / 128, DOc / 128), 256, 0, stream>>>(ch, sel, whT, b, out);
}